// Round 16
// baseline (101.613 us; speedup 1.0000x reference)
//
#include <hip/hip_runtime.h>

#define Bsz 4
#define Nn  256
#define OBSD 40
#define ACTD 8
#define HEADS 8
#define DIMD 32
#define Td  256
#define R   4   // rows per block

typedef unsigned short ushortT;

#define FMA4(accr, s, wv) do { \
    (accr).x = fmaf((s), (wv).x, (accr).x); \
    (accr).y = fmaf((s), (wv).y, (accr).y); \
    (accr).z = fmaf((s), (wv).z, (accr).z); \
    (accr).w = fmaf((s), (wv).w, (accr).w); } while (0)

__device__ __forceinline__ float b2f(ushortT u) {
    return __uint_as_float(((unsigned)u) << 16);
}
__device__ __forceinline__ ushortT f2b(float f) {     // round-to-nearest-even
    unsigned u = __float_as_uint(f);
    unsigned r = (u + 0x7FFFu + ((u >> 16) & 1u)) >> 16;
    return (ushortT)r;
}
__device__ __forceinline__ float4 b4f(const ushortT* p) {  // 8B aligned load + cvt
    ushort4 u = *(const ushort4*)p;
    return make_float4(b2f(u.x), b2f(u.y), b2f(u.z), b2f(u.w));
}

// K0: convert weights fp32 -> bf16 (once per launch; same work every call).
// grid 256 x 256 = 65536 threads.
__global__ void k_prep(const float* __restrict__ We1, const float* __restrict__ We2,
                       const float* __restrict__ Wn,  const float* __restrict__ Wh,
                       const float* __restrict__ Wl,
                       ushortT* __restrict__ We1b, ushortT* __restrict__ We2b,
                       ushortT* __restrict__ Wnb,  ushortT* __restrict__ Whb,
                       ushortT* __restrict__ Wlb) {
    int i = blockIdx.x * 256 + threadIdx.x;
    if (i < OBSD * Td) We1b[i] = f2b(We1[i]);
    We2b[i] = f2b(We2[i]);
    Wnb[i]  = f2b(Wn[i]);
    Whb[i]  = f2b(Wh[i]);
    Wlb[i]  = f2b(Wl[i]);
}

// K1: emb = relu(relu(obs @ We1 + be1) @ We2 + be2), R=4 rows/block, bf16 weights.
// grid 256 x 512. Blocks 0/1 zero snh/shid. emb stored bf16.
__global__ __launch_bounds__(512, 1) void k_emb(
                      const float* __restrict__ x,
                      const ushortT* __restrict__ We1b, const float* __restrict__ be1,
                      const ushortT* __restrict__ We2b, const float* __restrict__ be2,
                      ushortT* __restrict__ embb,
                      float* __restrict__ snh, float* __restrict__ shid) {
    int g = blockIdx.x;
    int t = threadIdx.x;
    int row0 = g * R;
    int b = row0 >> 8;
    int n0 = row0 & 255;
    if (g == 0)      { for (int i = t; i < Bsz * Td; i += 512) snh[i]  = 0.f; }
    else if (g == 1) { for (int i = t; i < Bsz * Td; i += 512) shid[i] = 0.f; }

    __shared__ float4 obs_t[OBSD];
    __shared__ float4 h1_t[Td];
    __shared__ float4 part[8][R][64];
    if (t < R * OBSD) {
        int r = t & (R - 1), k = t >> 2;
        ((float*)&obs_t[k])[r] = x[(b * (Nn + 1) + n0 + r) * OBSD + k];
    }
    __syncthreads();

    // Layer 1 (K=40): threads 0..255 own one column; chunks of 8 scalar bf16 loads.
    if (t < Td) {
        float bias1 = be1[t];
        float a1[R] = {bias1, bias1, bias1, bias1};
#pragma unroll
        for (int ch = 0; ch < 5; ++ch) {
            ushortT w[8];
#pragma unroll
            for (int p = 0; p < 8; ++p) w[p] = We1b[(ch * 8 + p) * Td + t];
#pragma unroll
            for (int p = 0; p < 8; ++p) {
                float wp = b2f(w[p]);
                float4 ov = obs_t[ch * 8 + p];
                a1[0] = fmaf(ov.x, wp, a1[0]);
                a1[1] = fmaf(ov.y, wp, a1[1]);
                a1[2] = fmaf(ov.z, wp, a1[2]);
                a1[3] = fmaf(ov.w, wp, a1[3]);
            }
        }
        h1_t[t] = make_float4(fmaxf(a1[0], 0.f), fmaxf(a1[1], 0.f),
                              fmaxf(a1[2], 0.f), fmaxf(a1[3], 0.f));
    }
    __syncthreads();

    // Layer 2: wave wv handles k in [32wv,+32); 4 chunks of 8 bf16x4 loads.
    int wv = t >> 6, c = t & 63;
    {
        float4 a2[R] = {};
#pragma unroll
        for (int ch = 0; ch < 4; ++ch) {
            int k0 = (wv << 5) + ch * 8;
            ushort4 w[8];
#pragma unroll
            for (int p = 0; p < 8; ++p)
                w[p] = *(const ushort4*)(We2b + (k0 + p) * Td + 4 * c);
#pragma unroll
            for (int p = 0; p < 8; ++p) {
                float4 w4 = make_float4(b2f(w[p].x), b2f(w[p].y), b2f(w[p].z), b2f(w[p].w));
                float4 hv = h1_t[k0 + p];
                FMA4(a2[0], hv.x, w4);
                FMA4(a2[1], hv.y, w4);
                FMA4(a2[2], hv.z, w4);
                FMA4(a2[3], hv.w, w4);
            }
        }
#pragma unroll
        for (int r = 0; r < R; ++r) part[wv][r][c] = a2[r];
    }
    __syncthreads();

    if (t < Td) {
        int c2 = t >> 2, j = t & 3;
#pragma unroll
        for (int r = 0; r < R; ++r) {
            float v = be2[t];
#pragma unroll
            for (int w2 = 0; w2 < 8; ++w2) v += ((const float*)&part[w2][r][c2])[j];
            embb[(row0 + r) * Td + t] = f2b(fmaxf(v, 0.f));
        }
    }
}

// K2: fused ne + Wn/Wh column-sum, R=4 m-rows/block, bf16 emb + weights.
// grid (64, 4) x 512.
__global__ __launch_bounds__(512, 1) void k_fused(
                        const float* __restrict__ adj, const ushortT* __restrict__ embb,
                        const ushortT* __restrict__ Wnb, const float* __restrict__ bn,
                        const ushortT* __restrict__ Whb, const float* __restrict__ bh,
                        float* __restrict__ snh, float* __restrict__ shid) {
    int g = blockIdx.x, b = blockIdx.y;
    int t = threadIdx.x;
    int m0 = g * R;
    __shared__ float4 arow_t[Nn];
    __shared__ float4 nrow_t[Td];
    __shared__ float4 partN[8][R][64];
    __shared__ float4 partH[8][R][64];
    if (t < Td)
        arow_t[t] = make_float4(adj[(m0 + 0) * Nn + t], adj[(m0 + 1) * Nn + t],
                                adj[(m0 + 2) * Nn + t], adj[(m0 + 3) * Nn + t]);
    __syncthreads();

    int wv = t >> 6, c = t & 63;
    const ushortT* eb = embb + b * Nn * Td;

    // Phase 1: ne. Wave wv sums n in [32wv,+32); 4 chunks of 8 bf16x4 loads.
    {
        float4 aN[R] = {};
#pragma unroll
        for (int ch = 0; ch < 4; ++ch) {
            int n0c = (wv << 5) + ch * 8;
            ushort4 e[8];
#pragma unroll
            for (int p = 0; p < 8; ++p)
                e[p] = *(const ushort4*)(eb + (n0c + p) * Td + 4 * c);
#pragma unroll
            for (int p = 0; p < 8; ++p) {
                float4 e4 = make_float4(b2f(e[p].x), b2f(e[p].y), b2f(e[p].z), b2f(e[p].w));
                float4 ar = arow_t[n0c + p];
                FMA4(aN[0], ar.x, e4);
                FMA4(aN[1], ar.y, e4);
                FMA4(aN[2], ar.z, e4);
                FMA4(aN[3], ar.w, e4);
            }
        }
#pragma unroll
        for (int r = 0; r < R; ++r) partN[wv][r][c] = aN[r];
    }
    __syncthreads();
    if (t < Td) {
        int c2 = t >> 2, j = t & 3;
        float nr[R];
#pragma unroll
        for (int r = 0; r < R; ++r) {
            float v = 0.f;
#pragma unroll
            for (int w2 = 0; w2 < 8; ++w2) v += ((const float*)&partN[w2][r][c2])[j];
            nr[r] = v;
        }
        nrow_t[t] = make_float4(nr[0], nr[1], nr[2], nr[3]);
    }
    __syncthreads();

    // Phase 2: Wn/Wh dual stream; 8 chunks of (4 Wn + 4 Wh) bf16x4 loads.
    {
        float4 sN[R] = {};
        float4 sH[R] = {};
#pragma unroll
        for (int ch = 0; ch < 8; ++ch) {
            int k0 = (wv << 5) + ch * 4;
            ushort4 wn[4], wh[4];
#pragma unroll
            for (int p = 0; p < 4; ++p)
                wn[p] = *(const ushort4*)(Wnb + (k0 + p) * Td + 4 * c);
#pragma unroll
            for (int p = 0; p < 4; ++p)
                wh[p] = *(const ushort4*)(Whb + (k0 + p) * Td + 4 * c);
#pragma unroll
            for (int p = 0; p < 4; ++p) {
                float4 wn4 = make_float4(b2f(wn[p].x), b2f(wn[p].y), b2f(wn[p].z), b2f(wn[p].w));
                float4 wh4 = make_float4(b2f(wh[p].x), b2f(wh[p].y), b2f(wh[p].z), b2f(wh[p].w));
                float4 nv = nrow_t[k0 + p];
                FMA4(sN[0], nv.x, wn4);  FMA4(sH[0], nv.x, wh4);
                FMA4(sN[1], nv.y, wn4);  FMA4(sH[1], nv.y, wh4);
                FMA4(sN[2], nv.z, wn4);  FMA4(sH[2], nv.z, wh4);
                FMA4(sN[3], nv.w, wn4);  FMA4(sH[3], nv.w, wh4);
            }
        }
#pragma unroll
        for (int r = 0; r < R; ++r) { partN[wv][r][c] = sN[r]; partH[wv][r][c] = sH[r]; }
    }
    __syncthreads();

    if (t < Td) {
        int c2 = t >> 2, j = t & 3;
        float bnt = bn[t], bht = bh[t];
        float rs1 = 0.f, rs2 = 0.f;
#pragma unroll
        for (int r = 0; r < R; ++r) {
            float v1 = bnt, v2 = bht;
#pragma unroll
            for (int w2 = 0; w2 < 8; ++w2) {
                v1 += ((const float*)&partN[w2][r][c2])[j];
                v2 += ((const float*)&partH[w2][r][c2])[j];
            }
            rs1 += fmaxf(v1, 0.f);
            rs2 += fmaxf(v2, 0.f);
        }
        atomicAdd(&snh[b * Td + t], rs1);
        atomicAdd(&shid[b * Td + t], rs2);
    }
}

// K3: per-batch target row -> ah -> softmax over DIM per head -> mean -> Wa
__global__ __launch_bounds__(256, 1) void k_final(
                        const float* __restrict__ x, const ushortT* __restrict__ embb,
                        const ushortT* __restrict__ Wlb, const float* __restrict__ bl,
                        const float* __restrict__ snh, const float* __restrict__ shid,
                        const float* __restrict__ Wa, const float* __restrict__ ba,
                        float* __restrict__ out) {
    int b = blockIdx.x;
    int t = threadIdx.x;
    int tgt = (int)x[(b * (Nn + 1) + Nn) * OBSD + 0];
    tgt = tgt < 0 ? 0 : (tgt > Nn - 1 ? Nn - 1 : tgt);
    __shared__ float erow[Td], lg[Td], pr[Td], od[DIMD];
    __shared__ float4 partL[4][64];
    erow[t] = b2f(embb[(b * Nn + tgt) * Td + t]);
    __syncthreads();

    int wv = t >> 6, c = t & 63;
    {
        float4 aL = {};
#pragma unroll
        for (int ch = 0; ch < 8; ++ch) {
            int k0 = (wv << 6) + ch * 8;
            ushort4 w[8];
#pragma unroll
            for (int p = 0; p < 8; ++p)
                w[p] = *(const ushort4*)(Wlb + (k0 + p) * Td + 4 * c);
#pragma unroll
            for (int p = 0; p < 8; ++p) {
                float4 w4 = make_float4(b2f(w[p].x), b2f(w[p].y), b2f(w[p].z), b2f(w[p].w));
                FMA4(aL, erow[k0 + p], w4);
            }
        }
        partL[wv][c] = aL;
    }
    __syncthreads();

    int c2 = t >> 2, j = t & 3;
    float acc = bl[t];
#pragma unroll
    for (int w2 = 0; w2 < 4; ++w2) acc += ((const float*)&partL[w2][c2])[j];
    float ah = fmaxf(acc, 0.f);
    lg[t] = ah * snh[b * Td + t];
    __syncthreads();
    int h = t & 7;
    float mx = -1e30f;
#pragma unroll
    for (int d = 0; d < DIMD; ++d) mx = fmaxf(mx, lg[d * HEADS + h]);
    float se = 0.f;
#pragma unroll
    for (int d = 0; d < DIMD; ++d) se += __expf(lg[d * HEADS + h] - mx);
    float attn = __expf(lg[t] - mx) / se;
    pr[t] = attn * shid[b * Td + t];
    __syncthreads();
    if (t < DIMD) {
        float s = 0.f;
#pragma unroll
        for (int hh = 0; hh < HEADS; ++hh) s += pr[t * HEADS + hh];
        od[t] = s * (1.f / HEADS);
    }
    __syncthreads();
    if (t < ACTD) {
        float s = ba[t];
#pragma unroll
        for (int d = 0; d < DIMD; ++d) s = fmaf(od[d], Wa[d * ACTD + t], s);
        out[b * ACTD + t] = s;
    }
}

extern "C" void kernel_launch(void* const* d_in, const int* in_sizes, int n_in,
                              void* d_out, int out_size, void* d_ws, size_t ws_size,
                              hipStream_t stream) {
    const float* x   = (const float*)d_in[0];
    const float* adj = (const float*)d_in[1];
    const float* We1 = (const float*)d_in[2];
    const float* be1 = (const float*)d_in[3];
    const float* We2 = (const float*)d_in[4];
    const float* be2 = (const float*)d_in[5];
    const float* Wl  = (const float*)d_in[6];
    const float* bl  = (const float*)d_in[7];
    const float* Wn  = (const float*)d_in[8];
    const float* bn  = (const float*)d_in[9];
    const float* Wh  = (const float*)d_in[10];
    const float* bh  = (const float*)d_in[11];
    const float* Wa  = (const float*)d_in[12];
    const float* ba  = (const float*)d_in[13];
    float* out = (float*)d_out;

    // ws layout (all 16B-aligned):
    //   embb  : bf16[B*N*T]   512 KB
    //   snh   : f32 [B*T]       4 KB
    //   shid  : f32 [B*T]       4 KB
    //   We1b  : bf16[40*256]   20 KB
    //   We2b/Wnb/Whb/Wlb : bf16[256*256] 128 KB each
    char* base = (char*)d_ws;
    ushortT* embb = (ushortT*)base;                 base += (size_t)Bsz * Nn * Td * 2;
    float*   snh  = (float*)base;                   base += Bsz * Td * 4;
    float*   shid = (float*)base;                   base += Bsz * Td * 4;
    ushortT* We1b = (ushortT*)base;                 base += OBSD * Td * 2 + 64;
    ushortT* We2b = (ushortT*)base;                 base += Td * Td * 2;
    ushortT* Wnb  = (ushortT*)base;                 base += Td * Td * 2;
    ushortT* Whb  = (ushortT*)base;                 base += Td * Td * 2;
    ushortT* Wlb  = (ushortT*)base;

    k_prep<<<dim3(256), dim3(256), 0, stream>>>(We1, We2, Wn, Wh, Wl,
                                                We1b, We2b, Wnb, Whb, Wlb);
    k_emb<<<dim3(Bsz * Nn / R), dim3(512), 0, stream>>>(x, We1b, be1, We2b, be2,
                                                        embb, snh, shid);
    k_fused<<<dim3(Nn / R, Bsz), dim3(512), 0, stream>>>(adj, embb, Wnb, bn, Whb, bh,
                                                         snh, shid);
    k_final<<<dim3(Bsz), dim3(256), 0, stream>>>(x, embb, Wlb, bl, snh, shid,
                                                 Wa, ba, out);
}